// Round 12
// baseline (247.621 us; speedup 1.0000x reference)
//
#include <hip/hip_runtime.h>

#define NFEAT 128
#define DOUT 48
#define NCAP 64               // per-node entry capacity (Poisson(16): P(deg>64) ~ 1e-19)
#define EPT 16                // edges per thread in bin path (4096/block, 391 blocks)
#define HSTRIDE 32            // hbf row stride in dwords (128B = one cache line)

typedef __attribute__((ext_vector_type(8))) short bf16x8;
typedef __attribute__((ext_vector_type(4))) float f32x4;

__device__ __forceinline__ float bf_lo(unsigned u) { return __uint_as_float(u << 16); }
__device__ __forceinline__ float bf_hi(unsigned u) { return __uint_as_float(u & 0xFFFF0000u); }
__device__ __forceinline__ unsigned bf_pack(float a, float b) {
    unsigned ua = __float_as_uint(a), ub = __float_as_uint(b);
    ua = (ua + 0x7FFFu + ((ua >> 16) & 1u)) >> 16;          // RN-even
    ub = (ub + 0x7FFFu + ((ub >> 16) & 1u)) & 0xFFFF0000u;
    return ua | ub;
}

// split fp32 into hi (truncated bf16) + lo (RN bf16 of residual); hh+hl+lh ~ 2^-14 rel err
__device__ __forceinline__ void split2(float x, short& hi, short& lo) {
    unsigned u = __float_as_uint(x);
    unsigned h = u & 0xFFFF0000u;
    hi = (short)(h >> 16);
    float r = x - __uint_as_float(h);
    unsigned v = __float_as_uint(r);
    lo = (short)((v + 0x7FFFu + ((v >> 16) & 1u)) >> 16);
}

// ---------------- kernel W-prep: pack W into (hi|lo<<16) bf16 pairs, once ----------------
__global__ __launch_bounds__(256) void k_wprep(
    const float* __restrict__ Ww, unsigned* __restrict__ Whl)
{
    int i = blockIdx.x * 256 + threadIdx.x;      // 6144 elements
    if (i < DOUT * NFEAT) {
        short h, l;
        split2(Ww[i], h, l);
        Whl[i] = (unsigned)(unsigned short)h | ((unsigned)(unsigned short)l << 16);
    }
}

// ---------------- fused proj + bin: block-specialized single launch ----------------
// Blocks [0, NBp): h = feat @ W^T + b via bf16 MFMA (hi/lo split), writes hbf/s_src/s_dst.
// Blocks [NBp, NBp+nbb): per-node binning -- one global atomicAdd on ncur[dst] and a 4B
// src-key store into the node's contiguous segment. No LDS, no per-block fixed work:
// hides completely under the proj blocks.
__global__ __launch_bounds__(256) void k_pb(
    const float* __restrict__ feat, const unsigned* __restrict__ Whl,
    const float* __restrict__ Wb, const float* __restrict__ attn_w,
    unsigned* __restrict__ hbf, float* __restrict__ s_src, float* __restrict__ s_dst,
    const int4* __restrict__ src4, const int4* __restrict__ dst4,
    int* __restrict__ ncur, unsigned* __restrict__ ents,
    int n, int nE, int NBp)
{
    __shared__ __align__(16) float hb[128][49];

    int tid = threadIdx.x;

    if (blockIdx.x < NBp) {
        // ======================= proj path =======================
        int lane = tid & 63;
        int wv   = tid >> 6;
        int g    = lane >> 4;          // k-group
        int r16  = lane & 15;          // A: row-in-tile, B: col-in-tile

        int mbase = blockIdx.x * 128 + wv * 32;
        int na0 = mbase + r16;       if (na0 >= n) na0 = n - 1;
        int na1 = mbase + 16 + r16;  if (na1 >= n) na1 = n - 1;

        const float* fA0 = feat + (size_t)na0 * NFEAT + g * 4;
        const float* fA1 = feat + (size_t)na1 * NFEAT + g * 4;
        const unsigned* wB = Whl + (size_t)r16 * NFEAT + g * 4;

        f32x4 acc[2][3];
#pragma unroll
        for (int mt = 0; mt < 2; ++mt)
#pragma unroll
            for (int nt = 0; nt < 3; ++nt)
                acc[mt][nt] = (f32x4){0.f, 0.f, 0.f, 0.f};

#pragma unroll
        for (int ks = 0; ks < 4; ++ks) {
            f32x4 ra[4];
            uint4 wb[6];
            ra[0] = *(const f32x4*)(fA0 + ks * 32);
            ra[1] = *(const f32x4*)(fA0 + ks * 32 + 16);
            ra[2] = *(const f32x4*)(fA1 + ks * 32);
            ra[3] = *(const f32x4*)(fA1 + ks * 32 + 16);
            wb[0] = *(const uint4*)(wB + ks * 32);
            wb[1] = *(const uint4*)(wB + ks * 32 + 16);
            wb[2] = *(const uint4*)(wB + 16 * NFEAT + ks * 32);
            wb[3] = *(const uint4*)(wB + 16 * NFEAT + ks * 32 + 16);
            wb[4] = *(const uint4*)(wB + 32 * NFEAT + ks * 32);
            wb[5] = *(const uint4*)(wB + 32 * NFEAT + ks * 32 + 16);

            bf16x8 Ah[2], Al[2], Bh[3], Bl[3];
#pragma unroll
            for (int t = 0; t < 2; ++t) {
#pragma unroll
                for (int i = 0; i < 4; ++i) {
                    short h, l;
                    split2(ra[2 * t][i], h, l);     Ah[t][i] = h;     Al[t][i] = l;
                    split2(ra[2 * t + 1][i], h, l); Ah[t][i + 4] = h; Al[t][i + 4] = l;
                }
            }
#pragma unroll
            for (int t = 0; t < 3; ++t) {
                unsigned w0 = wb[2 * t].x, w1 = wb[2 * t].y, w2 = wb[2 * t].z, w3 = wb[2 * t].w;
                unsigned v0 = wb[2 * t + 1].x, v1 = wb[2 * t + 1].y, v2 = wb[2 * t + 1].z, v3 = wb[2 * t + 1].w;
                Bh[t][0] = (short)(w0 & 0xFFFF); Bl[t][0] = (short)(w0 >> 16);
                Bh[t][1] = (short)(w1 & 0xFFFF); Bl[t][1] = (short)(w1 >> 16);
                Bh[t][2] = (short)(w2 & 0xFFFF); Bl[t][2] = (short)(w2 >> 16);
                Bh[t][3] = (short)(w3 & 0xFFFF); Bl[t][3] = (short)(w3 >> 16);
                Bh[t][4] = (short)(v0 & 0xFFFF); Bl[t][4] = (short)(v0 >> 16);
                Bh[t][5] = (short)(v1 & 0xFFFF); Bl[t][5] = (short)(v1 >> 16);
                Bh[t][6] = (short)(v2 & 0xFFFF); Bl[t][6] = (short)(v2 >> 16);
                Bh[t][7] = (short)(v3 & 0xFFFF); Bl[t][7] = (short)(v3 >> 16);
            }
#pragma unroll
            for (int mt = 0; mt < 2; ++mt)
#pragma unroll
                for (int nt = 0; nt < 3; ++nt) {
                    acc[mt][nt] = __builtin_amdgcn_mfma_f32_16x16x32_bf16(Ah[mt], Bh[nt], acc[mt][nt], 0, 0, 0);
                    acc[mt][nt] = __builtin_amdgcn_mfma_f32_16x16x32_bf16(Al[mt], Bh[nt], acc[mt][nt], 0, 0, 0);
                    acc[mt][nt] = __builtin_amdgcn_mfma_f32_16x16x32_bf16(Ah[mt], Bl[nt], acc[mt][nt], 0, 0, 0);
                }
        }

        // C/D -> LDS transpose: node_local = wv*32 + mt*16 + 4g + r, col = nt*16 + r16
#pragma unroll
        for (int mt = 0; mt < 2; ++mt)
#pragma unroll
            for (int nt = 0; nt < 3; ++nt)
#pragma unroll
                for (int rr = 0; rr < 4; ++rr)
                    hb[wv * 32 + mt * 16 + 4 * g + rr][nt * 16 + r16] = acc[mt][nt][rr];
        __syncthreads();

        // epilogue: 2 threads per node, 24 cols each
        int node = tid >> 1, part = tid & 1, jb = part * 24;
        int gn = blockIdx.x * 128 + node;
        float v[24];
        float ss = 0.f, sd = 0.f;
#pragma unroll
        for (int j = 0; j < 24; ++j) {
            float x = hb[node][jb + j] + Wb[jb + j];
            v[j] = x;
            ss = fmaf(x, attn_w[jb + j], ss);
            sd = fmaf(x, attn_w[DOUT + jb + j], sd);
        }
        ss += __shfl_xor(ss, 1, 64);
        sd += __shfl_xor(sd, 1, 64);

        if (gn < n) {
#pragma unroll
            for (int q = 0; q < 4; ++q) {
                int sub = part * 4 + q;                      // chunk s: cols 6s..6s+5
                uint4 u;
                u.x = bf_pack(v[6 * q + 0], v[6 * q + 1]);
                u.y = bf_pack(v[6 * q + 2], v[6 * q + 3]);
                u.z = bf_pack(v[6 * q + 4], v[6 * q + 5]);
                u.w = 0;
                *(uint4*)(hbf + (size_t)gn * HSTRIDE + sub * 4) = u;
            }
            if (part == 0) {
                s_src[gn] = ss;
                s_dst[gn] = sd;
            }
        }
    } else {
        // ======================= bin path (per-node segments) =======================
        int bb = blockIdx.x - NBp;
        long long e0 = (long long)bb * (256 * EPT) + (long long)tid * EPT;

        int s[EPT], d[EPT];
        bool any = (e0 < nE);
#pragma unroll
        for (int q = 0; q < EPT / 4; ++q) {
            int4 sv = any ? src4[e0 / 4 + q] : make_int4(0, 0, 0, 0);
            int4 dv = any ? dst4[e0 / 4 + q] : make_int4(0, 0, 0, 0);
            s[4 * q + 0] = sv.x; s[4 * q + 1] = sv.y; s[4 * q + 2] = sv.z; s[4 * q + 3] = sv.w;
            d[4 * q + 0] = dv.x; d[4 * q + 1] = dv.y; d[4 * q + 2] = dv.z; d[4 * q + 3] = dv.w;
        }

#pragma unroll
        for (int u = 0; u < EPT; ++u) {
            if (e0 + u < nE) {
                int slot = atomicAdd(&ncur[d[u]], 1);
                if (slot < NCAP)
                    ents[(size_t)d[u] * NCAP + slot] = (unsigned)s[u];
            }
        }
    }
}

// ---------------- softmax-aggregate: no sort, no LDS ----------------
// 8-lane group owns one node: keys contiguous at ents[node*64..], lane sub preloads
// keys sub, sub+8, ...; __shfl broadcasts within the group. Scores recomputed
// (s_dst[node] group-uniform, s_src L2-resident). 2 gathers in flight per group,
// 32 full-occupancy waves/CU of TLP on top.
__global__ __launch_bounds__(256) void k_aggb(
    const unsigned* __restrict__ hbf, const int* __restrict__ ncur,
    const unsigned* __restrict__ ents, const float* __restrict__ s_src,
    const float* __restrict__ s_dst, const float* __restrict__ attn_b,
    float* __restrict__ out, int n)
{
    int tid  = threadIdx.x;
    int lane = tid & 63;
    int grp  = tid >> 3;           // 0..31 in block
    int sub  = tid & 7;
    int gb   = lane & 56;          // 8-lane group base within wave
    float ab = attn_b[0];

#pragma unroll
    for (int pass = 0; pass < 2; ++pass) {
        int node = blockIdx.x * 64 + pass * 32 + grp;
        if (node < n) {
            int cnt = ncur[node];
            if (cnt > NCAP) cnt = NCAP;
            float sdn = s_dst[node] + ab;
            const unsigned* eb = ents + (size_t)node * NCAP;

            unsigned myk[8];
            int nru = (cnt + 7) >> 3;
#pragma unroll
            for (int u = 0; u < 8; ++u)
                myk[u] = (u < nru) ? eb[u * 8 + sub] : 0u;

            float a0 = 0.f, a1 = 0.f, a2 = 0.f, a3 = 0.f, a4 = 0.f, a5 = 0.f, den = 0.f;
#pragma unroll
            for (int u = 0; u < 8; ++u) {
                if (u * 8 >= cnt) break;
                int m = cnt - u * 8; if (m > 8) m = 8;
                int j = 0;
                for (; j + 1 < m; j += 2) {                  // 2 lines in flight per group
                    int i0 = (int)__shfl(myk[u], gb + j, 64);
                    int i1 = (int)__shfl(myk[u], gb + j + 1, 64);
                    float w0 = s_src[i0], w1 = s_src[i1];
                    uint4 h0 = *(const uint4*)(hbf + (size_t)i0 * HSTRIDE + sub * 4);
                    uint4 h1 = *(const uint4*)(hbf + (size_t)i1 * HSTRIDE + sub * 4);
                    float v0 = w0 + sdn; v0 = (v0 > 0.f) ? v0 : 0.2f * v0; float x0 = __expf(v0);
                    float v1 = w1 + sdn; v1 = (v1 > 0.f) ? v1 : 0.2f * v1; float x1 = __expf(v1);
                    den += x0; den += x1;
                    a0 = fmaf(x0, bf_lo(h0.x), a0); a1 = fmaf(x0, bf_hi(h0.x), a1);
                    a2 = fmaf(x0, bf_lo(h0.y), a2); a3 = fmaf(x0, bf_hi(h0.y), a3);
                    a4 = fmaf(x0, bf_lo(h0.z), a4); a5 = fmaf(x0, bf_hi(h0.z), a5);
                    a0 = fmaf(x1, bf_lo(h1.x), a0); a1 = fmaf(x1, bf_hi(h1.x), a1);
                    a2 = fmaf(x1, bf_lo(h1.y), a2); a3 = fmaf(x1, bf_hi(h1.y), a3);
                    a4 = fmaf(x1, bf_lo(h1.z), a4); a5 = fmaf(x1, bf_hi(h1.z), a5);
                }
                if (j < m) {
                    int i0 = (int)__shfl(myk[u], gb + j, 64);
                    float w0 = s_src[i0];
                    uint4 h0 = *(const uint4*)(hbf + (size_t)i0 * HSTRIDE + sub * 4);
                    float v0 = w0 + sdn; v0 = (v0 > 0.f) ? v0 : 0.2f * v0; float x0 = __expf(v0);
                    den += x0;
                    a0 = fmaf(x0, bf_lo(h0.x), a0); a1 = fmaf(x0, bf_hi(h0.x), a1);
                    a2 = fmaf(x0, bf_lo(h0.y), a2); a3 = fmaf(x0, bf_hi(h0.y), a3);
                    a4 = fmaf(x0, bf_lo(h0.z), a4); a5 = fmaf(x0, bf_hi(h0.z), a5);
                }
            }

            float inv = (cnt > 0) ? 1.f / den : 0.f;
            float* op = out + (size_t)node * DOUT + sub * 6;
            op[0] = a0 * inv;
            op[1] = a1 * inv;
            op[2] = a2 * inv;
            op[3] = a3 * inv;
            op[4] = a4 * inv;
            op[5] = a5 * inv;
        }
    }
}

extern "C" void kernel_launch(void* const* d_in, const int* in_sizes, int n_in,
                              void* d_out, int out_size, void* d_ws, size_t ws_size,
                              hipStream_t stream) {
    const float* feat   = (const float*)d_in[0];
    const float* Ww     = (const float*)d_in[1];
    const float* Wb     = (const float*)d_in[2];
    const float* attn_w = (const float*)d_in[3];
    const float* attn_b = (const float*)d_in[4];
    const int*   src    = (const int*)d_in[5];
    const int*   dst    = (const int*)d_in[6];

    int n  = in_sizes[0] / NFEAT;          // 100000
    int nE = in_sizes[5];                  // 1600000
    float* out = (float*)d_out;

    // workspace layout
    unsigned* hbf  = (unsigned*)d_ws;                      // n*32 uints (bf16 h, 128B rows)
    float* s_src   = (float*)(hbf + (size_t)n * HSTRIDE);  // n
    float* s_dst   = s_src + n;                            // n
    int*   ncur    = (int*)(s_dst + n);                    // n per-node cursors
    unsigned* ents = (unsigned*)(ncur + n);                // n*NCAP 4B src keys
    unsigned* Whl  = ents + (size_t)n * NCAP;              // DOUT*NFEAT packed hi/lo W

    hipMemsetAsync(ncur, 0, (size_t)n * sizeof(int), stream);

    k_wprep<<<(DOUT * NFEAT + 255) / 256, 256, 0, stream>>>(Ww, Whl);
    int NBp = (n + 127) / 128;                        // 782 proj blocks
    int nbb = (nE + 256 * EPT - 1) / (256 * EPT);     // 391 bin blocks
    k_pb<<<NBp + nbb, 256, 0, stream>>>(feat, Whl, Wb, attn_w, hbf, s_src, s_dst,
                                        (const int4*)src, (const int4*)dst,
                                        ncur, ents, n, nE, NBp);
    int NBa = (n + 63) / 64;                          // 1563 agg blocks
    k_aggb<<<NBa, 256, 0, stream>>>(hbf, ncur, ents, s_src, s_dst, attn_b, out, n);
}

// Round 13
// 165.682 us; speedup vs baseline: 1.4946x; 1.4946x over previous
//
#include <hip/hip_runtime.h>

#define NFEAT 128
#define DOUT 48
#define BSH 6                 // 64 nodes per bucket
#define BNODES 64
#define PCAP 192              // capacity per (bucket,class): mean 128, sigma 11.3
#define BCAP (PCAP * 8)       // 1536 entries per bucket
#define EPT 16                // edges per thread in bin path (4096/block, 391 blocks)
#define NBMAX 1568            // LDS histogram size (>= NB=1563)
#define HSTRIDE 32            // hbf row stride in dwords (128B = one cache line)

typedef __attribute__((ext_vector_type(8))) short bf16x8;
typedef __attribute__((ext_vector_type(4))) float f32x4;

__device__ __forceinline__ float bf_lo(unsigned u) { return __uint_as_float(u << 16); }
__device__ __forceinline__ float bf_hi(unsigned u) { return __uint_as_float(u & 0xFFFF0000u); }
__device__ __forceinline__ unsigned bf_pack(float a, float b) {
    unsigned ua = __float_as_uint(a), ub = __float_as_uint(b);
    ua = (ua + 0x7FFFu + ((ua >> 16) & 1u)) >> 16;          // RN-even
    ub = (ub + 0x7FFFu + ((ub >> 16) & 1u)) & 0xFFFF0000u;
    return ua | ub;
}

// split fp32 into hi (truncated bf16) + lo (RN bf16 of residual); hh+hl+lh ~ 2^-14 rel err
__device__ __forceinline__ void split2(float x, short& hi, short& lo) {
    unsigned u = __float_as_uint(x);
    unsigned h = u & 0xFFFF0000u;
    hi = (short)(h >> 16);
    float r = x - __uint_as_float(h);
    unsigned v = __float_as_uint(r);
    lo = (short)((v + 0x7FFFu + ((v >> 16) & 1u)) >> 16);
}

// ---------------- kernel W-prep: pack W into (hi|lo<<16) bf16 pairs, once ----------------
__global__ __launch_bounds__(256) void k_wprep(
    const float* __restrict__ Ww, unsigned* __restrict__ Whl)
{
    int i = blockIdx.x * 256 + threadIdx.x;      // 6144 elements
    if (i < DOUT * NFEAT) {
        short h, l;
        split2(Ww[i], h, l);
        Whl[i] = (unsigned)(unsigned short)h | ((unsigned)(unsigned short)l << 16);
    }
}

// ---------------- fused proj + bin: block-specialized single launch ----------------
// Blocks [0, NBp): h = feat @ W^T + b via bf16 MFMA (hi/lo split), writes hbf/s_src/s_dst.
// Blocks [NBp, NBp+nbb): bin edges by dst bucket, writing 4B KEYS only (src | dl<<17) --
// no dependence on s_src/s_dst (scores recomputed in k_aggb), so both paths overlap.
// Block-aggregated cursors keep per-bucket writes contiguous (write-coalescing layer --
// R12 showed removing it causes 8x write amplification).
__global__ __launch_bounds__(256) void k_pb(
    const float* __restrict__ feat, const unsigned* __restrict__ Whl,
    const float* __restrict__ Wb, const float* __restrict__ attn_w,
    unsigned* __restrict__ hbf, float* __restrict__ s_src, float* __restrict__ s_dst,
    const int4* __restrict__ src4, const int4* __restrict__ dst4,
    int* __restrict__ cursor, unsigned* __restrict__ ents,
    int n, int nE, int NB, int NBp)
{
    __shared__ __align__(16) char smem[128 * 49 * 4];

    int tid = threadIdx.x;

    if (blockIdx.x < NBp) {
        // ======================= proj path =======================
        float (*hb)[49] = (float(*)[49])smem;

        int lane = tid & 63;
        int wv   = tid >> 6;
        int g    = lane >> 4;          // k-group
        int r16  = lane & 15;          // A: row-in-tile, B: col-in-tile

        int mbase = blockIdx.x * 128 + wv * 32;
        int na0 = mbase + r16;       if (na0 >= n) na0 = n - 1;
        int na1 = mbase + 16 + r16;  if (na1 >= n) na1 = n - 1;

        const float* fA0 = feat + (size_t)na0 * NFEAT + g * 4;
        const float* fA1 = feat + (size_t)na1 * NFEAT + g * 4;
        const unsigned* wB = Whl + (size_t)r16 * NFEAT + g * 4;

        f32x4 acc[2][3];
#pragma unroll
        for (int mt = 0; mt < 2; ++mt)
#pragma unroll
            for (int nt = 0; nt < 3; ++nt)
                acc[mt][nt] = (f32x4){0.f, 0.f, 0.f, 0.f};

#pragma unroll
        for (int ks = 0; ks < 4; ++ks) {
            f32x4 ra[4];
            uint4 wb[6];
            ra[0] = *(const f32x4*)(fA0 + ks * 32);
            ra[1] = *(const f32x4*)(fA0 + ks * 32 + 16);
            ra[2] = *(const f32x4*)(fA1 + ks * 32);
            ra[3] = *(const f32x4*)(fA1 + ks * 32 + 16);
            wb[0] = *(const uint4*)(wB + ks * 32);
            wb[1] = *(const uint4*)(wB + ks * 32 + 16);
            wb[2] = *(const uint4*)(wB + 16 * NFEAT + ks * 32);
            wb[3] = *(const uint4*)(wB + 16 * NFEAT + ks * 32 + 16);
            wb[4] = *(const uint4*)(wB + 32 * NFEAT + ks * 32);
            wb[5] = *(const uint4*)(wB + 32 * NFEAT + ks * 32 + 16);

            bf16x8 Ah[2], Al[2], Bh[3], Bl[3];
#pragma unroll
            for (int t = 0; t < 2; ++t) {
#pragma unroll
                for (int i = 0; i < 4; ++i) {
                    short h, l;
                    split2(ra[2 * t][i], h, l);     Ah[t][i] = h;     Al[t][i] = l;
                    split2(ra[2 * t + 1][i], h, l); Ah[t][i + 4] = h; Al[t][i + 4] = l;
                }
            }
#pragma unroll
            for (int t = 0; t < 3; ++t) {
                unsigned w0 = wb[2 * t].x, w1 = wb[2 * t].y, w2 = wb[2 * t].z, w3 = wb[2 * t].w;
                unsigned v0 = wb[2 * t + 1].x, v1 = wb[2 * t + 1].y, v2 = wb[2 * t + 1].z, v3 = wb[2 * t + 1].w;
                Bh[t][0] = (short)(w0 & 0xFFFF); Bl[t][0] = (short)(w0 >> 16);
                Bh[t][1] = (short)(w1 & 0xFFFF); Bl[t][1] = (short)(w1 >> 16);
                Bh[t][2] = (short)(w2 & 0xFFFF); Bl[t][2] = (short)(w2 >> 16);
                Bh[t][3] = (short)(w3 & 0xFFFF); Bl[t][3] = (short)(w3 >> 16);
                Bh[t][4] = (short)(v0 & 0xFFFF); Bl[t][4] = (short)(v0 >> 16);
                Bh[t][5] = (short)(v1 & 0xFFFF); Bl[t][5] = (short)(v1 >> 16);
                Bh[t][6] = (short)(v2 & 0xFFFF); Bl[t][6] = (short)(v2 >> 16);
                Bh[t][7] = (short)(v3 & 0xFFFF); Bl[t][7] = (short)(v3 >> 16);
            }
#pragma unroll
            for (int mt = 0; mt < 2; ++mt)
#pragma unroll
                for (int nt = 0; nt < 3; ++nt) {
                    acc[mt][nt] = __builtin_amdgcn_mfma_f32_16x16x32_bf16(Ah[mt], Bh[nt], acc[mt][nt], 0, 0, 0);
                    acc[mt][nt] = __builtin_amdgcn_mfma_f32_16x16x32_bf16(Al[mt], Bh[nt], acc[mt][nt], 0, 0, 0);
                    acc[mt][nt] = __builtin_amdgcn_mfma_f32_16x16x32_bf16(Ah[mt], Bl[nt], acc[mt][nt], 0, 0, 0);
                }
        }

        // C/D -> LDS transpose: node_local = wv*32 + mt*16 + 4g + r, col = nt*16 + r16
#pragma unroll
        for (int mt = 0; mt < 2; ++mt)
#pragma unroll
            for (int nt = 0; nt < 3; ++nt)
#pragma unroll
                for (int rr = 0; rr < 4; ++rr)
                    hb[wv * 32 + mt * 16 + 4 * g + rr][nt * 16 + r16] = acc[mt][nt][rr];
        __syncthreads();

        // epilogue: 2 threads per node, 24 cols each
        int node = tid >> 1, part = tid & 1, jb = part * 24;
        int gn = blockIdx.x * 128 + node;
        float v[24];
        float ss = 0.f, sd = 0.f;
#pragma unroll
        for (int j = 0; j < 24; ++j) {
            float x = hb[node][jb + j] + Wb[jb + j];
            v[j] = x;
            ss = fmaf(x, attn_w[jb + j], ss);
            sd = fmaf(x, attn_w[DOUT + jb + j], sd);
        }
        ss += __shfl_xor(ss, 1, 64);
        sd += __shfl_xor(sd, 1, 64);

        if (gn < n) {
#pragma unroll
            for (int q = 0; q < 4; ++q) {
                int sub = part * 4 + q;                      // chunk s: cols 6s..6s+5
                uint4 u;
                u.x = bf_pack(v[6 * q + 0], v[6 * q + 1]);
                u.y = bf_pack(v[6 * q + 2], v[6 * q + 3]);
                u.z = bf_pack(v[6 * q + 4], v[6 * q + 5]);
                u.w = 0;
                *(uint4*)(hbf + (size_t)gn * HSTRIDE + sub * 4) = u;
            }
            if (part == 0) {
                s_src[gn] = ss;
                s_dst[gn] = sd;
            }
        }
    } else {
        // ======================= bin path (keys only) =======================
        int* hist = (int*)smem;
        int* bas  = hist + NBMAX;

        int bb  = blockIdx.x - NBp;
        int cls = bb & 7;
        long long e0 = (long long)bb * (256 * EPT) + (long long)tid * EPT;

        for (int t = tid; t < NB; t += 256) hist[t] = 0;
        __syncthreads();

        int s[EPT], d[EPT];
        bool any = (e0 < nE);
#pragma unroll
        for (int q = 0; q < EPT / 4; ++q) {
            int4 sv = any ? src4[e0 / 4 + q] : make_int4(0, 0, 0, 0);
            int4 dv = any ? dst4[e0 / 4 + q] : make_int4(0, 0, 0, 0);
            s[4 * q + 0] = sv.x; s[4 * q + 1] = sv.y; s[4 * q + 2] = sv.z; s[4 * q + 3] = sv.w;
            d[4 * q + 0] = dv.x; d[4 * q + 1] = dv.y; d[4 * q + 2] = dv.z; d[4 * q + 3] = dv.w;
        }

        int rank[EPT];
#pragma unroll
        for (int u = 0; u < EPT; ++u)
            rank[u] = (e0 + u < nE) ? atomicAdd(&hist[d[u] >> BSH], 1) : 0;
        __syncthreads();

        for (int t = tid; t < NB; t += 256) {
            int c = hist[t];
            if (c > 0) bas[t] = atomicAdd(cursor + cls * NB + t, c);
        }
        __syncthreads();

#pragma unroll
        for (int u = 0; u < EPT; ++u) {
            if (e0 + u < nE) {
                int bkt = d[u] >> BSH;
                int slot = bas[bkt] + rank[u];
                if (slot < PCAP)
                    ents[(size_t)bkt * BCAP + cls * PCAP + slot] =
                        (unsigned)s[u] | ((unsigned)(d[u] & (BNODES - 1)) << 17);
            }
        }
    }
}

// ---------------- fused sort + softmax-aggregate: one block per bucket ----------------
// 4B key entries; scores recomputed here: s_dst[node] group-uniform, s_src L2-resident.
// 8-lane group owns one node, 4 gather lines in flight per group.
__global__ __launch_bounds__(256) void k_aggb(
    const unsigned* __restrict__ hbf, const int* __restrict__ cursor,
    const unsigned* __restrict__ ents, const float* __restrict__ s_src,
    const float* __restrict__ s_dst, const float* __restrict__ attn_b,
    float* __restrict__ out, int n, int NB)
{
    __shared__ unsigned se[BCAP];
    __shared__ unsigned short sidx[BCAP];
    __shared__ int c1[BNODES], c2[BNODES], lrp[BNODES + 1];
    __shared__ int cp[9];

    int b = blockIdx.x;
    int tid = threadIdx.x;
    const unsigned* ebase = ents + (size_t)b * BCAP;
    float ab = attn_b[0];

    if (tid < BNODES) { c1[tid] = 0; c2[tid] = 0; }
    if (tid < 8) {
        int c = min(cursor[tid * NB + b], PCAP);             // class-major cursor layout
        int p = c;
#pragma unroll
        for (int o = 1; o < 8; o <<= 1) {
            int u = __shfl_up(p, o, 64);
            if (tid >= o) p += u;
        }
        cp[tid + 1] = p;
        if (tid == 0) cp[0] = 0;
    }
    __syncthreads();
    int total = cp[8];

    // pass A: stage keys into LDS (uniform per-class loops) + histogram dst-local
#pragma unroll
    for (int c = 0; c < 8; ++c) {
        int s0 = cp[c], s1 = cp[c + 1];
        for (int i = s0 + tid; i < s1; i += 256) {
            unsigned v = ebase[c * PCAP + (i - s0)];
            se[i] = v;
            atomicAdd(&c1[v >> 17], 1);
        }
    }
    __syncthreads();

    if (tid < BNODES) {
        int v = c1[tid];
        int p = v;
#pragma unroll
        for (int o = 1; o < 64; o <<= 1) {
            int u = __shfl_up(p, o, 64);
            if (tid >= o) p += u;
        }
        lrp[tid] = p - v;
        if (tid == BNODES - 1) lrp[BNODES] = p;
    }
    __syncthreads();

    // pass B: index-sort by dst-local (LDS -> LDS)
    for (int i = tid; i < total; i += 256) {
        int dl = (int)(se[i] >> 17);
        int pos = lrp[dl] + atomicAdd(&c2[dl], 1);
        sidx[pos] = (unsigned short)i;
    }
    __syncthreads();

    // aggregate: group = 8 lanes = one node; lane's sub owns cols 6*sub..6*sub+5
    int grp = tid >> 3;            // 0..31
    int sub = tid & 7;
#pragma unroll
    for (int pass = 0; pass < 2; ++pass) {
        int dl = grp + pass * 32;
        int node = (b << BSH) + dl;
        bool live = (node < n);
        float sdn = live ? (s_dst[node] + ab) : 0.f;         // group-uniform
        int st = lrp[dl];
        int en = live ? lrp[dl + 1] : st;
        float a0 = 0.f, a1 = 0.f, a2 = 0.f, a3 = 0.f, a4 = 0.f, a5 = 0.f, den = 0.f;
        int k = st;
        for (; k + 3 < en; k += 4) {                         // 4 lines in flight per group
            int i0 = se[sidx[k]]     & 0x1FFFF;
            int i1 = se[sidx[k + 1]] & 0x1FFFF;
            int i2 = se[sidx[k + 2]] & 0x1FFFF;
            int i3 = se[sidx[k + 3]] & 0x1FFFF;
            float w0 = s_src[i0], w1 = s_src[i1], w2 = s_src[i2], w3 = s_src[i3];
            uint4 h0 = *(const uint4*)(hbf + (size_t)i0 * HSTRIDE + sub * 4);
            uint4 h1 = *(const uint4*)(hbf + (size_t)i1 * HSTRIDE + sub * 4);
            uint4 h2 = *(const uint4*)(hbf + (size_t)i2 * HSTRIDE + sub * 4);
            uint4 h3 = *(const uint4*)(hbf + (size_t)i3 * HSTRIDE + sub * 4);
            float v0 = w0 + sdn; v0 = (v0 > 0.f) ? v0 : 0.2f * v0; float x0 = __expf(v0);
            float v1 = w1 + sdn; v1 = (v1 > 0.f) ? v1 : 0.2f * v1; float x1 = __expf(v1);
            float v2 = w2 + sdn; v2 = (v2 > 0.f) ? v2 : 0.2f * v2; float x2 = __expf(v2);
            float v3 = w3 + sdn; v3 = (v3 > 0.f) ? v3 : 0.2f * v3; float x3 = __expf(v3);
            den += x0; den += x1; den += x2; den += x3;
            a0 = fmaf(x0, bf_lo(h0.x), a0); a1 = fmaf(x0, bf_hi(h0.x), a1);
            a2 = fmaf(x0, bf_lo(h0.y), a2); a3 = fmaf(x0, bf_hi(h0.y), a3);
            a4 = fmaf(x0, bf_lo(h0.z), a4); a5 = fmaf(x0, bf_hi(h0.z), a5);
            a0 = fmaf(x1, bf_lo(h1.x), a0); a1 = fmaf(x1, bf_hi(h1.x), a1);
            a2 = fmaf(x1, bf_lo(h1.y), a2); a3 = fmaf(x1, bf_hi(h1.y), a3);
            a4 = fmaf(x1, bf_lo(h1.z), a4); a5 = fmaf(x1, bf_hi(h1.z), a5);
            a0 = fmaf(x2, bf_lo(h2.x), a0); a1 = fmaf(x2, bf_hi(h2.x), a1);
            a2 = fmaf(x2, bf_lo(h2.y), a2); a3 = fmaf(x2, bf_hi(h2.y), a3);
            a4 = fmaf(x2, bf_lo(h2.z), a4); a5 = fmaf(x2, bf_hi(h2.z), a5);
            a0 = fmaf(x3, bf_lo(h3.x), a0); a1 = fmaf(x3, bf_hi(h3.x), a1);
            a2 = fmaf(x3, bf_lo(h3.y), a2); a3 = fmaf(x3, bf_hi(h3.y), a3);
            a4 = fmaf(x3, bf_lo(h3.z), a4); a5 = fmaf(x3, bf_hi(h3.z), a5);
        }
        for (; k < en; ++k) {
            int i0 = se[sidx[k]] & 0x1FFFF;
            float w0 = s_src[i0];
            uint4 h0 = *(const uint4*)(hbf + (size_t)i0 * HSTRIDE + sub * 4);
            float v0 = w0 + sdn; v0 = (v0 > 0.f) ? v0 : 0.2f * v0; float x0 = __expf(v0);
            den += x0;
            a0 = fmaf(x0, bf_lo(h0.x), a0); a1 = fmaf(x0, bf_hi(h0.x), a1);
            a2 = fmaf(x0, bf_lo(h0.y), a2); a3 = fmaf(x0, bf_hi(h0.y), a3);
            a4 = fmaf(x0, bf_lo(h0.z), a4); a5 = fmaf(x0, bf_hi(h0.z), a5);
        }
        if (live) {
            float inv = (en > st) ? 1.f / den : 0.f;
            float* op = out + (size_t)node * DOUT + sub * 6;
            op[0] = a0 * inv;
            op[1] = a1 * inv;
            op[2] = a2 * inv;
            op[3] = a3 * inv;
            op[4] = a4 * inv;
            op[5] = a5 * inv;
        }
    }
}

extern "C" void kernel_launch(void* const* d_in, const int* in_sizes, int n_in,
                              void* d_out, int out_size, void* d_ws, size_t ws_size,
                              hipStream_t stream) {
    const float* feat   = (const float*)d_in[0];
    const float* Ww     = (const float*)d_in[1];
    const float* Wb     = (const float*)d_in[2];
    const float* attn_w = (const float*)d_in[3];
    const float* attn_b = (const float*)d_in[4];
    const int*   src    = (const int*)d_in[5];
    const int*   dst    = (const int*)d_in[6];

    int n  = in_sizes[0] / NFEAT;          // 100000
    int nE = in_sizes[5];                  // 1600000
    int NB = (n + BNODES - 1) / BNODES;    // 1563 buckets
    int N8 = NB * 8;                       // class-major cursors
    float* out = (float*)d_out;

    // workspace layout
    unsigned* hbf  = (unsigned*)d_ws;                      // n*32 uints (bf16 h, 128B rows)
    float* s_src   = (float*)(hbf + (size_t)n * HSTRIDE);  // n
    float* s_dst   = s_src + n;                            // n
    int*   cursor  = (int*)(s_dst + n);                    // N8
    unsigned* ents = (unsigned*)(cursor + N8);             // NB*BCAP 4B keys
    unsigned* Whl  = ents + (size_t)NB * BCAP;             // DOUT*NFEAT packed hi/lo W

    hipMemsetAsync(cursor, 0, (size_t)N8 * sizeof(int), stream);

    k_wprep<<<(DOUT * NFEAT + 255) / 256, 256, 0, stream>>>(Ww, Whl);
    int NBp = (n + 127) / 128;                        // 782 proj blocks
    int nbb = (nE + 256 * EPT - 1) / (256 * EPT);     // 391 bin blocks
    k_pb<<<NBp + nbb, 256, 0, stream>>>(feat, Whl, Wb, attn_w, hbf, s_src, s_dst,
                                        (const int4*)src, (const int4*)dst,
                                        cursor, ents, n, nE, NB, NBp);
    k_aggb<<<NB, 256, 0, stream>>>(hbf, cursor, ents, s_src, s_dst, attn_b, out, n, NB);
}

// Round 14
// 165.569 us; speedup vs baseline: 1.4956x; 1.0007x over previous
//
#include <hip/hip_runtime.h>

#define NFEAT 128
#define DOUT 48
#define BSH 6                 // 64 nodes per bucket
#define BNODES 64
#define PCAP 192              // capacity per (bucket,class): mean 128, sigma 11.3
#define BCAP (PCAP * 8)       // 1536 entries per bucket
#define EPT 16                // edges per thread in bin path (4096/block, 391 blocks)
#define NBMAX 1568            // LDS histogram size (>= NB=1563)
#define HSTRIDE 32            // hbf row stride in dwords (128B = one cache line)

typedef __attribute__((ext_vector_type(8))) short bf16x8;
typedef __attribute__((ext_vector_type(4))) float f32x4;

__device__ __forceinline__ float bf_lo(unsigned u) { return __uint_as_float(u << 16); }
__device__ __forceinline__ float bf_hi(unsigned u) { return __uint_as_float(u & 0xFFFF0000u); }
__device__ __forceinline__ unsigned bf_pack(float a, float b) {
    unsigned ua = __float_as_uint(a), ub = __float_as_uint(b);
    ua = (ua + 0x7FFFu + ((ua >> 16) & 1u)) >> 16;          // RN-even
    ub = (ub + 0x7FFFu + ((ub >> 16) & 1u)) & 0xFFFF0000u;
    return ua | ub;
}

// split fp32 into hi (truncated bf16) + lo (RN bf16 of residual); hh+hl+lh ~ 2^-14 rel err
__device__ __forceinline__ void split2(float x, short& hi, short& lo) {
    unsigned u = __float_as_uint(x);
    unsigned h = u & 0xFFFF0000u;
    hi = (short)(h >> 16);
    float r = x - __uint_as_float(h);
    unsigned v = __float_as_uint(r);
    lo = (short)((v + 0x7FFFu + ((v >> 16) & 1u)) >> 16);
}

// ---------------- kernel W-prep: pack W into (hi|lo<<16) bf16 pairs, once ----------------
__global__ __launch_bounds__(256) void k_wprep(
    const float* __restrict__ Ww, unsigned* __restrict__ Whl)
{
    int i = blockIdx.x * 256 + threadIdx.x;      // 6144 elements
    if (i < DOUT * NFEAT) {
        short h, l;
        split2(Ww[i], h, l);
        Whl[i] = (unsigned)(unsigned short)h | ((unsigned)(unsigned short)l << 16);
    }
}

// ---------------- fused proj + bin: block-specialized single launch ----------------
// Blocks [0, NBp): h = feat @ W^T + b via bf16 MFMA (hi/lo split), writes hbf/s_src/s_dst.
//   All 16 feat loads issued UP FRONT (ra[4][4]) -- 16-deep MLP on the HBM-cold stream;
//   R13 PMC showed VGPR=60 (no hoist) and all pipes idle = serial load->use latency wall.
// Blocks [NBp, NBp+nbb): bin edges by dst bucket, writing 4B KEYS only (src | dl<<17) --
// no dependence on s_src/s_dst (scores recomputed in k_aggb), so both paths overlap.
// Block-aggregated cursors keep per-bucket writes contiguous (R12: removing them = 8x
// write amplification).
__global__ __launch_bounds__(256) void k_pb(
    const float* __restrict__ feat, const unsigned* __restrict__ Whl,
    const float* __restrict__ Wb, const float* __restrict__ attn_w,
    unsigned* __restrict__ hbf, float* __restrict__ s_src, float* __restrict__ s_dst,
    const int4* __restrict__ src4, const int4* __restrict__ dst4,
    int* __restrict__ cursor, unsigned* __restrict__ ents,
    int n, int nE, int NB, int NBp)
{
    __shared__ __align__(16) char smem[128 * 49 * 4];

    int tid = threadIdx.x;

    if (blockIdx.x < NBp) {
        // ======================= proj path =======================
        float (*hb)[49] = (float(*)[49])smem;

        int lane = tid & 63;
        int wv   = tid >> 6;
        int g    = lane >> 4;          // k-group
        int r16  = lane & 15;          // A: row-in-tile, B: col-in-tile

        int mbase = blockIdx.x * 128 + wv * 32;
        int na0 = mbase + r16;       if (na0 >= n) na0 = n - 1;
        int na1 = mbase + 16 + r16;  if (na1 >= n) na1 = n - 1;

        const float* fA0 = feat + (size_t)na0 * NFEAT + g * 4;
        const float* fA1 = feat + (size_t)na1 * NFEAT + g * 4;
        const unsigned* wB = Whl + (size_t)r16 * NFEAT + g * 4;

        // issue ALL feat loads first: 16-deep memory-level parallelism on the cold stream
        f32x4 ra[4][4];
#pragma unroll
        for (int ks = 0; ks < 4; ++ks) {
            ra[ks][0] = *(const f32x4*)(fA0 + ks * 32);
            ra[ks][1] = *(const f32x4*)(fA0 + ks * 32 + 16);
            ra[ks][2] = *(const f32x4*)(fA1 + ks * 32);
            ra[ks][3] = *(const f32x4*)(fA1 + ks * 32 + 16);
        }

        f32x4 acc[2][3];
#pragma unroll
        for (int mt = 0; mt < 2; ++mt)
#pragma unroll
            for (int nt = 0; nt < 3; ++nt)
                acc[mt][nt] = (f32x4){0.f, 0.f, 0.f, 0.f};

#pragma unroll
        for (int ks = 0; ks < 4; ++ks) {
            uint4 wb[6];
            wb[0] = *(const uint4*)(wB + ks * 32);
            wb[1] = *(const uint4*)(wB + ks * 32 + 16);
            wb[2] = *(const uint4*)(wB + 16 * NFEAT + ks * 32);
            wb[3] = *(const uint4*)(wB + 16 * NFEAT + ks * 32 + 16);
            wb[4] = *(const uint4*)(wB + 32 * NFEAT + ks * 32);
            wb[5] = *(const uint4*)(wB + 32 * NFEAT + ks * 32 + 16);

            bf16x8 Ah[2], Al[2], Bh[3], Bl[3];
#pragma unroll
            for (int t = 0; t < 2; ++t) {
#pragma unroll
                for (int i = 0; i < 4; ++i) {
                    short h, l;
                    split2(ra[ks][2 * t][i], h, l);     Ah[t][i] = h;     Al[t][i] = l;
                    split2(ra[ks][2 * t + 1][i], h, l); Ah[t][i + 4] = h; Al[t][i + 4] = l;
                }
            }
#pragma unroll
            for (int t = 0; t < 3; ++t) {
                unsigned w0 = wb[2 * t].x, w1 = wb[2 * t].y, w2 = wb[2 * t].z, w3 = wb[2 * t].w;
                unsigned v0 = wb[2 * t + 1].x, v1 = wb[2 * t + 1].y, v2 = wb[2 * t + 1].z, v3 = wb[2 * t + 1].w;
                Bh[t][0] = (short)(w0 & 0xFFFF); Bl[t][0] = (short)(w0 >> 16);
                Bh[t][1] = (short)(w1 & 0xFFFF); Bl[t][1] = (short)(w1 >> 16);
                Bh[t][2] = (short)(w2 & 0xFFFF); Bl[t][2] = (short)(w2 >> 16);
                Bh[t][3] = (short)(w3 & 0xFFFF); Bl[t][3] = (short)(w3 >> 16);
                Bh[t][4] = (short)(v0 & 0xFFFF); Bl[t][4] = (short)(v0 >> 16);
                Bh[t][5] = (short)(v1 & 0xFFFF); Bl[t][5] = (short)(v1 >> 16);
                Bh[t][6] = (short)(v2 & 0xFFFF); Bl[t][6] = (short)(v2 >> 16);
                Bh[t][7] = (short)(v3 & 0xFFFF); Bl[t][7] = (short)(v3 >> 16);
            }
#pragma unroll
            for (int mt = 0; mt < 2; ++mt)
#pragma unroll
                for (int nt = 0; nt < 3; ++nt) {
                    acc[mt][nt] = __builtin_amdgcn_mfma_f32_16x16x32_bf16(Ah[mt], Bh[nt], acc[mt][nt], 0, 0, 0);
                    acc[mt][nt] = __builtin_amdgcn_mfma_f32_16x16x32_bf16(Al[mt], Bh[nt], acc[mt][nt], 0, 0, 0);
                    acc[mt][nt] = __builtin_amdgcn_mfma_f32_16x16x32_bf16(Ah[mt], Bl[nt], acc[mt][nt], 0, 0, 0);
                }
        }

        // C/D -> LDS transpose: node_local = wv*32 + mt*16 + 4g + r, col = nt*16 + r16
#pragma unroll
        for (int mt = 0; mt < 2; ++mt)
#pragma unroll
            for (int nt = 0; nt < 3; ++nt)
#pragma unroll
                for (int rr = 0; rr < 4; ++rr)
                    hb[wv * 32 + mt * 16 + 4 * g + rr][nt * 16 + r16] = acc[mt][nt][rr];
        __syncthreads();

        // epilogue: 2 threads per node, 24 cols each
        int node = tid >> 1, part = tid & 1, jb = part * 24;
        int gn = blockIdx.x * 128 + node;
        float v[24];
        float ss = 0.f, sd = 0.f;
#pragma unroll
        for (int j = 0; j < 24; ++j) {
            float x = hb[node][jb + j] + Wb[jb + j];
            v[j] = x;
            ss = fmaf(x, attn_w[jb + j], ss);
            sd = fmaf(x, attn_w[DOUT + jb + j], sd);
        }
        ss += __shfl_xor(ss, 1, 64);
        sd += __shfl_xor(sd, 1, 64);

        if (gn < n) {
#pragma unroll
            for (int q = 0; q < 4; ++q) {
                int sub = part * 4 + q;                      // chunk s: cols 6s..6s+5
                uint4 u;
                u.x = bf_pack(v[6 * q + 0], v[6 * q + 1]);
                u.y = bf_pack(v[6 * q + 2], v[6 * q + 3]);
                u.z = bf_pack(v[6 * q + 4], v[6 * q + 5]);
                u.w = 0;
                *(uint4*)(hbf + (size_t)gn * HSTRIDE + sub * 4) = u;
            }
            if (part == 0) {
                s_src[gn] = ss;
                s_dst[gn] = sd;
            }
        }
    } else {
        // ======================= bin path (keys only) =======================
        int* hist = (int*)smem;
        int* bas  = hist + NBMAX;

        int bb  = blockIdx.x - NBp;
        int cls = bb & 7;
        long long e0 = (long long)bb * (256 * EPT) + (long long)tid * EPT;

        for (int t = tid; t < NB; t += 256) hist[t] = 0;
        __syncthreads();

        int s[EPT], d[EPT];
        bool any = (e0 < nE);
#pragma unroll
        for (int q = 0; q < EPT / 4; ++q) {
            int4 sv = any ? src4[e0 / 4 + q] : make_int4(0, 0, 0, 0);
            int4 dv = any ? dst4[e0 / 4 + q] : make_int4(0, 0, 0, 0);
            s[4 * q + 0] = sv.x; s[4 * q + 1] = sv.y; s[4 * q + 2] = sv.z; s[4 * q + 3] = sv.w;
            d[4 * q + 0] = dv.x; d[4 * q + 1] = dv.y; d[4 * q + 2] = dv.z; d[4 * q + 3] = dv.w;
        }

        int rank[EPT];
#pragma unroll
        for (int u = 0; u < EPT; ++u)
            rank[u] = (e0 + u < nE) ? atomicAdd(&hist[d[u] >> BSH], 1) : 0;
        __syncthreads();

        for (int t = tid; t < NB; t += 256) {
            int c = hist[t];
            if (c > 0) bas[t] = atomicAdd(cursor + cls * NB + t, c);
        }
        __syncthreads();

#pragma unroll
        for (int u = 0; u < EPT; ++u) {
            if (e0 + u < nE) {
                int bkt = d[u] >> BSH;
                int slot = bas[bkt] + rank[u];
                if (slot < PCAP)
                    ents[(size_t)bkt * BCAP + cls * PCAP + slot] =
                        (unsigned)s[u] | ((unsigned)(d[u] & (BNODES - 1)) << 17);
            }
        }
    }
}

// ---------------- fused sort + softmax-aggregate: one block per bucket ----------------
// 4B key entries; scores recomputed here: s_dst[node] group-uniform, s_src L2-resident.
// 8-lane group owns one node, 4 gather lines in flight per group.
__global__ __launch_bounds__(256) void k_aggb(
    const unsigned* __restrict__ hbf, const int* __restrict__ cursor,
    const unsigned* __restrict__ ents, const float* __restrict__ s_src,
    const float* __restrict__ s_dst, const float* __restrict__ attn_b,
    float* __restrict__ out, int n, int NB)
{
    __shared__ unsigned se[BCAP];
    __shared__ unsigned short sidx[BCAP];
    __shared__ int c1[BNODES], c2[BNODES], lrp[BNODES + 1];
    __shared__ int cp[9];

    int b = blockIdx.x;
    int tid = threadIdx.x;
    const unsigned* ebase = ents + (size_t)b * BCAP;
    float ab = attn_b[0];

    if (tid < BNODES) { c1[tid] = 0; c2[tid] = 0; }
    if (tid < 8) {
        int c = min(cursor[tid * NB + b], PCAP);             // class-major cursor layout
        int p = c;
#pragma unroll
        for (int o = 1; o < 8; o <<= 1) {
            int u = __shfl_up(p, o, 64);
            if (tid >= o) p += u;
        }
        cp[tid + 1] = p;
        if (tid == 0) cp[0] = 0;
    }
    __syncthreads();
    int total = cp[8];

    // pass A: stage keys into LDS (uniform per-class loops) + histogram dst-local
#pragma unroll
    for (int c = 0; c < 8; ++c) {
        int s0 = cp[c], s1 = cp[c + 1];
        for (int i = s0 + tid; i < s1; i += 256) {
            unsigned v = ebase[c * PCAP + (i - s0)];
            se[i] = v;
            atomicAdd(&c1[v >> 17], 1);
        }
    }
    __syncthreads();

    if (tid < BNODES) {
        int v = c1[tid];
        int p = v;
#pragma unroll
        for (int o = 1; o < 64; o <<= 1) {
            int u = __shfl_up(p, o, 64);
            if (tid >= o) p += u;
        }
        lrp[tid] = p - v;
        if (tid == BNODES - 1) lrp[BNODES] = p;
    }
    __syncthreads();

    // pass B: index-sort by dst-local (LDS -> LDS)
    for (int i = tid; i < total; i += 256) {
        int dl = (int)(se[i] >> 17);
        int pos = lrp[dl] + atomicAdd(&c2[dl], 1);
        sidx[pos] = (unsigned short)i;
    }
    __syncthreads();

    // aggregate: group = 8 lanes = one node; lane's sub owns cols 6*sub..6*sub+5
    int grp = tid >> 3;            // 0..31
    int sub = tid & 7;
#pragma unroll
    for (int pass = 0; pass < 2; ++pass) {
        int dl = grp + pass * 32;
        int node = (b << BSH) + dl;
        bool live = (node < n);
        float sdn = live ? (s_dst[node] + ab) : 0.f;         // group-uniform
        int st = lrp[dl];
        int en = live ? lrp[dl + 1] : st;
        float a0 = 0.f, a1 = 0.f, a2 = 0.f, a3 = 0.f, a4 = 0.f, a5 = 0.f, den = 0.f;
        int k = st;
        for (; k + 3 < en; k += 4) {                         // 4 lines in flight per group
            int i0 = se[sidx[k]]     & 0x1FFFF;
            int i1 = se[sidx[k + 1]] & 0x1FFFF;
            int i2 = se[sidx[k + 2]] & 0x1FFFF;
            int i3 = se[sidx[k + 3]] & 0x1FFFF;
            float w0 = s_src[i0], w1 = s_src[i1], w2 = s_src[i2], w3 = s_src[i3];
            uint4 h0 = *(const uint4*)(hbf + (size_t)i0 * HSTRIDE + sub * 4);
            uint4 h1 = *(const uint4*)(hbf + (size_t)i1 * HSTRIDE + sub * 4);
            uint4 h2 = *(const uint4*)(hbf + (size_t)i2 * HSTRIDE + sub * 4);
            uint4 h3 = *(const uint4*)(hbf + (size_t)i3 * HSTRIDE + sub * 4);
            float v0 = w0 + sdn; v0 = (v0 > 0.f) ? v0 : 0.2f * v0; float x0 = __expf(v0);
            float v1 = w1 + sdn; v1 = (v1 > 0.f) ? v1 : 0.2f * v1; float x1 = __expf(v1);
            float v2 = w2 + sdn; v2 = (v2 > 0.f) ? v2 : 0.2f * v2; float x2 = __expf(v2);
            float v3 = w3 + sdn; v3 = (v3 > 0.f) ? v3 : 0.2f * v3; float x3 = __expf(v3);
            den += x0; den += x1; den += x2; den += x3;
            a0 = fmaf(x0, bf_lo(h0.x), a0); a1 = fmaf(x0, bf_hi(h0.x), a1);
            a2 = fmaf(x0, bf_lo(h0.y), a2); a3 = fmaf(x0, bf_hi(h0.y), a3);
            a4 = fmaf(x0, bf_lo(h0.z), a4); a5 = fmaf(x0, bf_hi(h0.z), a5);
            a0 = fmaf(x1, bf_lo(h1.x), a0); a1 = fmaf(x1, bf_hi(h1.x), a1);
            a2 = fmaf(x1, bf_lo(h1.y), a2); a3 = fmaf(x1, bf_hi(h1.y), a3);
            a4 = fmaf(x1, bf_lo(h1.z), a4); a5 = fmaf(x1, bf_hi(h1.z), a5);
            a0 = fmaf(x2, bf_lo(h2.x), a0); a1 = fmaf(x2, bf_hi(h2.x), a1);
            a2 = fmaf(x2, bf_lo(h2.y), a2); a3 = fmaf(x2, bf_hi(h2.y), a3);
            a4 = fmaf(x2, bf_lo(h2.z), a4); a5 = fmaf(x2, bf_hi(h2.z), a5);
            a0 = fmaf(x3, bf_lo(h3.x), a0); a1 = fmaf(x3, bf_hi(h3.x), a1);
            a2 = fmaf(x3, bf_lo(h3.y), a2); a3 = fmaf(x3, bf_hi(h3.y), a3);
            a4 = fmaf(x3, bf_lo(h3.z), a4); a5 = fmaf(x3, bf_hi(h3.z), a5);
        }
        for (; k < en; ++k) {
            int i0 = se[sidx[k]] & 0x1FFFF;
            float w0 = s_src[i0];
            uint4 h0 = *(const uint4*)(hbf + (size_t)i0 * HSTRIDE + sub * 4);
            float v0 = w0 + sdn; v0 = (v0 > 0.f) ? v0 : 0.2f * v0; float x0 = __expf(v0);
            den += x0;
            a0 = fmaf(x0, bf_lo(h0.x), a0); a1 = fmaf(x0, bf_hi(h0.x), a1);
            a2 = fmaf(x0, bf_lo(h0.y), a2); a3 = fmaf(x0, bf_hi(h0.y), a3);
            a4 = fmaf(x0, bf_lo(h0.z), a4); a5 = fmaf(x0, bf_hi(h0.z), a5);
        }
        if (live) {
            float inv = (en > st) ? 1.f / den : 0.f;
            float* op = out + (size_t)node * DOUT + sub * 6;
            op[0] = a0 * inv;
            op[1] = a1 * inv;
            op[2] = a2 * inv;
            op[3] = a3 * inv;
            op[4] = a4 * inv;
            op[5] = a5 * inv;
        }
    }
}

extern "C" void kernel_launch(void* const* d_in, const int* in_sizes, int n_in,
                              void* d_out, int out_size, void* d_ws, size_t ws_size,
                              hipStream_t stream) {
    const float* feat   = (const float*)d_in[0];
    const float* Ww     = (const float*)d_in[1];
    const float* Wb     = (const float*)d_in[2];
    const float* attn_w = (const float*)d_in[3];
    const float* attn_b = (const float*)d_in[4];
    const int*   src    = (const int*)d_in[5];
    const int*   dst    = (const int*)d_in[6];

    int n  = in_sizes[0] / NFEAT;          // 100000
    int nE = in_sizes[5];                  // 1600000
    int NB = (n + BNODES - 1) / BNODES;    // 1563 buckets
    int N8 = NB * 8;                       // class-major cursors
    float* out = (float*)d_out;

    // workspace layout
    unsigned* hbf  = (unsigned*)d_ws;                      // n*32 uints (bf16 h, 128B rows)
    float* s_src   = (float*)(hbf + (size_t)n * HSTRIDE);  // n
    float* s_dst   = s_src + n;                            // n
    int*   cursor  = (int*)(s_dst + n);                    // N8
    unsigned* ents = (unsigned*)(cursor + N8);             // NB*BCAP 4B keys
    unsigned* Whl  = ents + (size_t)NB * BCAP;             // DOUT*NFEAT packed hi/lo W

    hipMemsetAsync(cursor, 0, (size_t)N8 * sizeof(int), stream);

    k_wprep<<<(DOUT * NFEAT + 255) / 256, 256, 0, stream>>>(Ww, Whl);
    int NBp = (n + 127) / 128;                        // 782 proj blocks
    int nbb = (nE + 256 * EPT - 1) / (256 * EPT);     // 391 bin blocks
    k_pb<<<NBp + nbb, 256, 0, stream>>>(feat, Whl, Wb, attn_w, hbf, s_src, s_dst,
                                        (const int4*)src, (const int4*)dst,
                                        cursor, ents, n, nE, NB, NBp);
    k_aggb<<<NB, 256, 0, stream>>>(hbf, cursor, ents, s_src, s_dst, attn_b, out, n, NB);
}